// Round 1
// baseline (539.962 us; speedup 1.0000x reference)
//
#include <hip/hip_runtime.h>
#include <cmath>

typedef short short8 __attribute__((ext_vector_type(8)));
typedef float f32x4 __attribute__((ext_vector_type(4)));

#define EPSF 1.1920929e-07f

// ---------------- LDS layout (bytes) ----------------
// x tile:   xA [32][18] f32, xB [32][18] f32
// A1/A2*:   [32][264] bf16 (pitch 264 => 528B rows, 16B aligned)
// RAWW:     [32][528] f32, within-row layout d*33+k (d<16,k<32)
// RAWH:     [32][528] f32 split: rows 0-15 at RAWH1, rows 16-31 overlay A2W+A1
#define LDS_XA    0
#define LDS_XB    2304
#define LDS_A2H   4608
#define LDS_A2W   21504
#define LDS_A1    38400
#define LDS_RAWW  55296
#define LDS_RAWH1 122880
#define LDS_RAWH2 21504
#define LDS_TOTAL 156672

// packed weight element offsets (ushort elements) in d_ws
// tiles: 2H:128 (8kt x 16nt), 2W:128, 3H:272 (8 x 34, cols>=528 zero), 3W:256 (8 x 32)
#define OFF2H 0
#define OFF2W 65536
#define OFF3H 131072
#define OFF3W 270336

__device__ __forceinline__ unsigned short f2bf(float f) {
  union { float f; unsigned u; } v; v.f = f;
  return (unsigned short)((v.u + 0x7FFFu + ((v.u >> 16) & 1u)) >> 16);
}

// ---------------- weight packing into MFMA B-fragment order ----------------
// B-frag for mfma_f32_16x16x32_bf16: lane l holds B[k=(l>>4)*8+e][n=l&15]
__global__ void pack_weights(const float* __restrict__ hW2, const float* __restrict__ wW2,
                             const float* __restrict__ hW3, const float* __restrict__ wW3,
                             unsigned short* __restrict__ out) {
  int tile = blockIdx.x;
  int l = threadIdx.x;
  const float* src; unsigned short* dst; int NT, N, base;
  if (tile < 128)      { src = hW2; dst = out + OFF2H; NT = 16; N = 256; base = tile; }
  else if (tile < 256) { src = wW2; dst = out + OFF2W; NT = 16; N = 256; base = tile - 128; }
  else if (tile < 528) { src = hW3; dst = out + OFF3H; NT = 34; N = 528; base = tile - 256; }
  else                 { src = wW3; dst = out + OFF3W; NT = 32; N = 512; base = tile - 528; }
  int nt = base % NT, kt = base / NT;
  int col = nt * 16 + (l & 15);
  int k0 = kt * 32 + (l >> 4) * 8;
  short8 v;
  #pragma unroll
  for (int e = 0; e < 8; e++) {
    float f = (col < N) ? src[(k0 + e) * N + col] : 0.f;
    v[e] = (short)f2bf(f);
  }
  *(short8*)(dst + (base * 64 + l) * 8) = v;
}

// ---------------- fused kernel helpers ----------------
// L1: a1 = relu(xA @ W1 + b1) on fp32 VALU, result bf16 into LDS_A1.
__device__ __forceinline__ void mlp_l1(char* lds, const float* __restrict__ W1,
                                       const float* __restrict__ b1) {
  int t = threadIdx.x;
  int j = t & 255, rh = t >> 8;
  float w[16];
  #pragma unroll
  for (int i = 0; i < 16; i++) w[i] = W1[i * 256 + j];
  float bj = b1[j];
  unsigned short* a1 = (unsigned short*)(lds + LDS_A1);
  const float* xa = (const float*)(lds + LDS_XA);
  #pragma unroll
  for (int rr = 0; rr < 16; rr++) {
    int r = rh * 16 + rr;
    float acc = bj;
    #pragma unroll
    for (int i = 0; i < 16; i++) acc = fmaf(xa[r * 18 + i], w[i], acc);
    a1[r * 264 + j] = f2bf(fmaxf(acc, 0.f));
  }
}

// GEMM: C[32][NT*16] = A(LDS bf16) @ Bpacked + bias.
// MODE 0: relu -> bf16 LDS at oOff (pitch 264)
// MODE 1: f32 -> RAWW, within-row offset (col>>5)*33 + (col&31)
// MODE 2: f32 -> RAWH split (col<528 only)
template <int MODE, int NT, int NSRC>
__device__ __forceinline__ void gemm_phase(char* lds, int aOff,
                                           const unsigned short* __restrict__ pB,
                                           const float* __restrict__ bias, int oOff) {
  int t = threadIdx.x;
  int w = t >> 6, l = t & 63;
  int lc = l & 15, lq = l >> 4;
  const unsigned short* A = (const unsigned short*)(lds + aOff);
  for (int ct = w; ct < NT; ct += 8) {
    f32x4 acc0 = {0.f, 0.f, 0.f, 0.f};
    f32x4 acc1 = {0.f, 0.f, 0.f, 0.f};
    #pragma unroll
    for (int kt = 0; kt < 8; kt++) {
      short8 bfr = *(const short8*)(pB + ((kt * NT + ct) * 64 + l) * 8);
      short8 a0 = *(const short8*)(A + lc * 264 + kt * 32 + lq * 8);
      short8 a1 = *(const short8*)(A + (16 + lc) * 264 + kt * 32 + lq * 8);
      acc0 = __builtin_amdgcn_mfma_f32_16x16x32_bf16(a0, bfr, acc0, 0, 0, 0);
      acc1 = __builtin_amdgcn_mfma_f32_16x16x32_bf16(a1, bfr, acc1, 0, 0, 0);
    }
    int col = ct * 16 + lc;
    float b = (col < NSRC) ? bias[col] : 0.f;
    #pragma unroll
    for (int rg = 0; rg < 4; rg++) {
      int rowt = lq * 4 + rg;  // C row = (lane>>4)*4 + reg  [m89-verified]
      float v0 = acc0[rg] + b;
      float v1 = acc1[rg] + b;
      if (MODE == 0) {
        unsigned short* o = (unsigned short*)(lds + oOff);
        o[rowt * 264 + col] = f2bf(fmaxf(v0, 0.f));
        o[(16 + rowt) * 264 + col] = f2bf(fmaxf(v1, 0.f));
      } else if (MODE == 1) {
        float* o = (float*)(lds + oOff);
        int cc = (col >> 5) * 33 + (col & 31);
        o[rowt * 528 + cc] = v0;
        o[(16 + rowt) * 528 + cc] = v1;
      } else {
        if (col < 528) {
          float* o1 = (float*)(lds + LDS_RAWH1);
          float* o2 = (float*)(lds + LDS_RAWH2);
          o1[rowt * 528 + col] = v0;
          o2[rowt * 528 + col] = v1;
        }
      }
    }
  }
}

__global__ __launch_bounds__(512) void fused_kernel(
    const float* __restrict__ x,
    const float* __restrict__ hW1, const float* __restrict__ hb1,
    const float* __restrict__ hb2, const float* __restrict__ hb3,
    const float* __restrict__ wW1, const float* __restrict__ wb1,
    const float* __restrict__ wb2, const float* __restrict__ wb3,
    const unsigned short* __restrict__ pw,
    float* __restrict__ y) {
  extern __shared__ char lds[];
  const int t = threadIdx.x;
  const int r0 = blockIdx.x * 32;

  // load x tile, split even cols -> xA, odd cols -> xB
  if (t < 256) {
    int row = t >> 3, c4 = t & 7;
    float4 v = *(const float4*)(x + (r0 + row) * 32 + c4 * 4);
    float* xa = (float*)(lds + LDS_XA) + row * 18;
    float* xb = (float*)(lds + LDS_XB) + row * 18;
    xa[c4 * 2] = v.x;     xb[c4 * 2] = v.y;
    xa[c4 * 2 + 1] = v.z; xb[c4 * 2 + 1] = v.w;
  }
  __syncthreads();

  mlp_l1(lds, wW1, wb1);                                            // a1w -> A1
  __syncthreads();
  gemm_phase<0, 16, 256>(lds, LDS_A1, pw + OFF2W, wb2, LDS_A2W);    // a2w
  __syncthreads();
  mlp_l1(lds, hW1, hb1);                                            // a1h -> A1
  __syncthreads();
  gemm_phase<0, 16, 256>(lds, LDS_A1, pw + OFF2H, hb2, LDS_A2H);    // a2h
  __syncthreads();
  gemm_phase<1, 32, 512>(lds, LDS_A2W, pw + OFF3W, wb3, LDS_RAWW);  // raw_w
  __syncthreads();
  gemm_phase<2, 34, 528>(lds, LDS_A2H, pw + OFF3H, hb3, 0);         // raw_h (overlays A2W+A1)
  __syncthreads();

  // spline: one (row,d) pair per thread; streaming, no indexed reg arrays
  {
    int row = t >> 4, d = t & 15;
    float* RW = (float*)(lds + LDS_RAWW) + row * 528 + d * 33;
    float* RH = (float*)(lds + (row < 16 ? LDS_RAWH1 : LDS_RAWH2)) + (row & 15) * 528 + d * 33;
    float xb = ((float*)(lds + LDS_XB))[row * 18 + d];
    // softmax over 32 widths
    float m = -1e30f;
    for (int k = 0; k < 32; k++) m = fmaxf(m, RW[k]);
    float s = 0.f;
    for (int k = 0; k < 32; k++) { float e = __expf(RW[k] - m); s += e; RW[k] = e; }
    float inv_s = 1.f / s;
    // heights = softplus(raw_h)+EPS (in place), total trapezoid area
    float r0v = RH[0];
    float hp = fmaxf(r0v, 0.f) + log1pf(__expf(-fabsf(r0v))) + EPSF;
    RH[0] = hp;
    float total = 0.f;
    for (int k = 0; k < 32; k++) {
      float rv = RH[k + 1];
      float hn = fmaxf(rv, 0.f) + log1pf(__expf(-fabsf(rv))) + EPSF;
      RH[k + 1] = hn;
      total += 0.5f * (hp + hn) * (RW[k] * inv_s);
      hp = hn;
    }
    float invT = 1.f / total;
    // streaming bin search + select (i = last k with xb >= bins[k], k<=31)
    float bl = 0.f, cl = 0.f;
    float sxl = 0.f, sw = 0.f, svl = 0.f, svr = 0.f, scl = 0.f;
    float hk = RH[0];
    for (int k = 0; k < 32; k++) {
      float wk = RW[k] * inv_s;
      float hk1 = RH[k + 1];
      float area = 0.5f * (hk + hk1) * wk * invT;
      if (xb >= bl) { sxl = bl; sw = wk; svl = hk * invT; svr = hk1 * invT; scl = cl; }
      bl += wk; cl += area; hk = hk1;
    }
    float alpha = (xb - sxl) / (sw + EPSF);
    float yv = scl + 0.5f * alpha * alpha * (svr - svl) * sw + alpha * svl * sw;
    ((float*)(lds + LDS_XB))[row * 18 + d] = yv;
  }
  __syncthreads();

  // write y: even cols original, odd cols spline output
  if (t < 256) {
    int row = t >> 3, c4 = t & 7;
    float* xa = (float*)(lds + LDS_XA) + row * 18;
    float* xb = (float*)(lds + LDS_XB) + row * 18;
    float4 v;
    v.x = xa[c4 * 2]; v.y = xb[c4 * 2];
    v.z = xa[c4 * 2 + 1]; v.w = xb[c4 * 2 + 1];
    *(float4*)(y + (r0 + row) * 32 + c4 * 4) = v;
  }
}

extern "C" void kernel_launch(void* const* d_in, const int* in_sizes, int n_in,
                              void* d_out, int out_size, void* d_ws, size_t ws_size,
                              hipStream_t stream) {
  const float* x   = (const float*)d_in[0];
  const float* hW1 = (const float*)d_in[1];
  const float* hb1 = (const float*)d_in[2];
  const float* hW2 = (const float*)d_in[3];
  const float* hb2 = (const float*)d_in[4];
  const float* hW3 = (const float*)d_in[5];
  const float* hb3 = (const float*)d_in[6];
  const float* wW1 = (const float*)d_in[7];
  const float* wb1 = (const float*)d_in[8];
  const float* wW2 = (const float*)d_in[9];
  const float* wb2 = (const float*)d_in[10];
  const float* wW3 = (const float*)d_in[11];
  const float* wb3 = (const float*)d_in[12];
  unsigned short* pw = (unsigned short*)d_ws;

  pack_weights<<<784, 64, 0, stream>>>(hW2, wW2, hW3, wW3, pw);

  hipFuncSetAttribute((const void*)fused_kernel,
                      hipFuncAttributeMaxDynamicSharedMemorySize, LDS_TOTAL);
  fused_kernel<<<4096, 512, LDS_TOTAL, stream>>>(
      x, hW1, hb1, hb2, hb3, wW1, wb1, wb2, wb3, pw, (float*)d_out);
}

// Round 2
// 258.047 us; speedup vs baseline: 2.0925x; 2.0925x over previous
//
#include <hip/hip_runtime.h>
#include <cmath>

typedef short short8 __attribute__((ext_vector_type(8)));
typedef float f32x4 __attribute__((ext_vector_type(4)));

#define EPSF 1.1920929e-07f

// ---------------- LDS layout (bytes), total 69632 (2 blocks/CU) ----------------
#define LDS_XA   0        // [32][32]  ushort bf16 xA, K zero-padded to 32 (2048 B)
#define LDS_A1   2048     // [32][264] ushort (16896 B)
#define LDS_A2W  18944    // [32][264] ushort
#define LDS_A2H  35840    // [32][264] ushort
#define LDS_EW   2048     // [16][528] ushort e=exp(raw_w), layout d*33+k  (overlays A1)
#define LDS_HH   52736    // [16][528] ushort h=softplus(raw_h)+EPS, layout d*33+k
#define LDS_TOTAL 69632

// ---------------- packed weights (ushort elements) in d_ws ----------------
// B-frag for mfma_f32_16x16x32_bf16: lane l holds B[k=(l>>4)*8+e][n=l&15]
// tile = 512 ushort. [kt][nt][lane][8] order per matrix.
#define OFF1H 0        // 16 tiles  (K=16 padded to 32)
#define OFF1W 8192
#define OFF2H 16384    // 128 tiles (8 kt x 16 nt)
#define OFF2W 81920
#define OFF3H 147456   // 272 tiles (8 kt x 34 nt, cols>=528 zero)
#define OFF3W 286720   // 256 tiles (8 kt x 32 nt)   total 417792 ushort = 835584 B

__device__ __forceinline__ unsigned short f2bf(float f) {
  union { float f; unsigned u; } v; v.f = f;
  return (unsigned short)((v.u + 0x7FFFu + ((v.u >> 16) & 1u)) >> 16);
}
__device__ __forceinline__ float bf2f(unsigned short h) {
  union { unsigned u; float f; } v; v.u = ((unsigned)h) << 16; return v.f;
}

__global__ void pack_weights(const float* __restrict__ hW1, const float* __restrict__ wW1,
                             const float* __restrict__ hW2, const float* __restrict__ wW2,
                             const float* __restrict__ hW3, const float* __restrict__ wW3,
                             unsigned short* __restrict__ out) {
  int tile = blockIdx.x, l = threadIdx.x;
  const float* src; unsigned short* dst; int NT, N, K, base;
  if (tile < 16)       { src = hW1; dst = out + OFF1H; NT = 16; N = 256; K = 16;  base = tile; }
  else if (tile < 32)  { src = wW1; dst = out + OFF1W; NT = 16; N = 256; K = 16;  base = tile - 16; }
  else if (tile < 160) { src = hW2; dst = out + OFF2H; NT = 16; N = 256; K = 256; base = tile - 32; }
  else if (tile < 288) { src = wW2; dst = out + OFF2W; NT = 16; N = 256; K = 256; base = tile - 160; }
  else if (tile < 560) { src = hW3; dst = out + OFF3H; NT = 34; N = 528; K = 256; base = tile - 288; }
  else                 { src = wW3; dst = out + OFF3W; NT = 32; N = 512; K = 256; base = tile - 560; }
  int nt = base % NT, kt = base / NT;
  int col = nt * 16 + (l & 15);
  int k0 = kt * 32 + (l >> 4) * 8;
  short8 v;
  #pragma unroll
  for (int e = 0; e < 8; e++) {
    float f = (col < N && (k0 + e) < K) ? src[(k0 + e) * N + col] : 0.f;
    v[e] = (short)f2bf(f);
  }
  *(short8*)(dst + (base * 64 + l) * 8) = v;
}

// GEMM -> relu -> bf16 LDS (pitch 264). M=32 (two row-tiles share each B-frag), NT=16.
template <int KT, int APITCH>
__device__ __forceinline__ void gemm_relu(char* lds, int aOff,
                                          const unsigned short* __restrict__ pB,
                                          const float* __restrict__ bias, int oOff) {
  int t = threadIdx.x, w = t >> 6, l = t & 63, lc = l & 15, lq = l >> 4;
  const unsigned short* A = (const unsigned short*)(lds + aOff);
  unsigned short* o = (unsigned short*)(lds + oOff);
  #pragma unroll
  for (int ci = 0; ci < 2; ci++) {
    int ct = w + ci * 8;
    f32x4 acc0 = {0.f, 0.f, 0.f, 0.f};
    f32x4 acc1 = {0.f, 0.f, 0.f, 0.f};
    #pragma unroll
    for (int kt = 0; kt < KT; kt++) {
      short8 bfr = *(const short8*)(pB + ((kt * 16 + ct) * 64 + l) * 8);
      short8 a0 = *(const short8*)(A + lc * APITCH + kt * 32 + lq * 8);
      short8 a1 = *(const short8*)(A + (16 + lc) * APITCH + kt * 32 + lq * 8);
      acc0 = __builtin_amdgcn_mfma_f32_16x16x32_bf16(a0, bfr, acc0, 0, 0, 0);
      acc1 = __builtin_amdgcn_mfma_f32_16x16x32_bf16(a1, bfr, acc1, 0, 0, 0);
    }
    int col = ct * 16 + lc;
    float bv = bias[col];
    #pragma unroll
    for (int rg = 0; rg < 4; rg++) {
      int rowt = lq * 4 + rg;  // C row = (lane>>4)*4 + reg  [m89-verified]
      o[rowt * 264 + col] = f2bf(fmaxf(acc0[rg] + bv, 0.f));
      o[(16 + rowt) * 264 + col] = f2bf(fmaxf(acc1[rg] + bv, 0.f));
    }
  }
}

// G3 half-tile (M=16, rows rbase..rbase+15).
// MODE 0: widths, NT=32 -> EW[row][ (col>>5)*33 + (col&31) ] = bf16(exp(raw))
// MODE 1: heights, NT=34 -> HH[row][col] = bf16(softplus(raw)+EPS), col<528
template <int MODE>
__device__ __forceinline__ void gemm_g3(char* lds, int aOff, int rbase,
                                        const unsigned short* __restrict__ pB,
                                        const float* __restrict__ bias) {
  const int NT = MODE ? 34 : 32;
  int t = threadIdx.x, w = t >> 6, l = t & 63, lc = l & 15, lq = l >> 4;
  const unsigned short* A = (const unsigned short*)(lds + aOff);
  for (int ct = w; ct < NT; ct += 8) {
    f32x4 acc = {0.f, 0.f, 0.f, 0.f};
    #pragma unroll
    for (int kt = 0; kt < 8; kt++) {
      short8 bfr = *(const short8*)(pB + ((kt * NT + ct) * 64 + l) * 8);
      short8 a = *(const short8*)(A + (rbase + lc) * 264 + kt * 32 + lq * 8);
      acc = __builtin_amdgcn_mfma_f32_16x16x32_bf16(a, bfr, acc, 0, 0, 0);
    }
    int col = ct * 16 + lc;
    if (MODE == 0) {
      unsigned short* EW = (unsigned short*)(lds + LDS_EW);
      float bv = bias[col];
      int cc = (col >> 5) * 33 + (col & 31);
      #pragma unroll
      for (int rg = 0; rg < 4; rg++)
        EW[(lq * 4 + rg) * 528 + cc] = f2bf(__expf(acc[rg] + bv));
    } else {
      if (col < 528) {
        unsigned short* HH = (unsigned short*)(lds + LDS_HH);
        float bv = bias[col];
        #pragma unroll
        for (int rg = 0; rg < 4; rg++) {
          float v = acc[rg] + bv;
          float sp = fmaxf(v, 0.f) + __logf(1.f + __expf(-fabsf(v))) + EPSF;
          HH[(lq * 4 + rg) * 528 + col] = f2bf(sp);
        }
      }
    }
  }
}

__global__ __launch_bounds__(512, 4) void fused_kernel(
    const float* __restrict__ x,
    const float* __restrict__ hb1, const float* __restrict__ hb2, const float* __restrict__ hb3,
    const float* __restrict__ wb1, const float* __restrict__ wb2, const float* __restrict__ wb3,
    const unsigned short* __restrict__ pw,
    float* __restrict__ y) {
  extern __shared__ char lds[];
  const int t = threadIdx.x;
  const int r0 = blockIdx.x * 32;

  // load x tile: write y evens directly, stage xA as bf16 [32][32] (K-pad zeros)
  if (t < 256) {
    int row = t >> 3, c4 = t & 7;
    float4 v = *(const float4*)(x + (r0 + row) * 32 + c4 * 4);
    y[(r0 + row) * 32 + c4 * 4] = v.x;
    y[(r0 + row) * 32 + c4 * 4 + 2] = v.z;
    unsigned short* xa = (unsigned short*)(lds + LDS_XA);
    xa[row * 32 + c4 * 2] = f2bf(v.x);
    xa[row * 32 + c4 * 2 + 1] = f2bf(v.z);
  } else {
    int idx = t - 256;
    int row = idx >> 3, j = idx & 7;
    ((unsigned*)(lds + LDS_XA))[row * 16 + 8 + j] = 0u;
  }
  __syncthreads();

  gemm_relu<1, 32>(lds, LDS_XA, pw + OFF1W, wb1, LDS_A1);   // a1w
  __syncthreads();
  gemm_relu<8, 264>(lds, LDS_A1, pw + OFF2W, wb2, LDS_A2W); // a2w
  __syncthreads();
  gemm_relu<1, 32>(lds, LDS_XA, pw + OFF1H, hb1, LDS_A1);   // a1h
  __syncthreads();
  gemm_relu<8, 264>(lds, LDS_A1, pw + OFF2H, hb2, LDS_A2H); // a2h
  __syncthreads();

  #pragma unroll
  for (int h = 0; h < 2; h++) {
    gemm_g3<0>(lds, LDS_A2W, h * 16, pw + OFF3W, wb3);  // e  -> EW (overlays dead A1)
    gemm_g3<1>(lds, LDS_A2H, h * 16, pw + OFF3H, hb3);  // h  -> HH
    __syncthreads();

    if (t < 256) {
      int row16 = t >> 4, d = t & 15;
      const unsigned short* EW = (const unsigned short*)(lds + LDS_EW) + row16 * 528 + d * 33;
      const unsigned short* HH = (const unsigned short*)(lds + LDS_HH) + row16 * 528 + d * 33;
      int grow = r0 + h * 16 + row16;
      float xb = x[grow * 32 + 2 * d + 1];
      float s = 0.f;
      for (int k = 0; k < 32; k++) s += bf2f(EW[k]);
      float inv_s = 1.f / s;
      float hk = bf2f(HH[0]);
      float bl = 0.f, cl = 0.f;
      float sxl = 0.f, sw = 0.f, shl = hk, shr = hk, scl = 0.f;
      for (int k = 0; k < 32; k++) {
        float wk = bf2f(EW[k]) * inv_s;
        float hk1 = bf2f(HH[k + 1]);
        if (xb >= bl) { sxl = bl; sw = wk; shl = hk; shr = hk1; scl = cl; }
        cl += 0.5f * (hk + hk1) * wk;
        bl += wk;
        hk = hk1;
      }
      float invT = 1.f / cl;
      float alpha = (xb - sxl) / (sw + EPSF);
      float yv = (scl + (0.5f * alpha * alpha * (shr - shl) + alpha * shl) * sw) * invT;
      y[grow * 32 + 2 * d + 1] = yv;
    }
    __syncthreads();
  }
}

extern "C" void kernel_launch(void* const* d_in, const int* in_sizes, int n_in,
                              void* d_out, int out_size, void* d_ws, size_t ws_size,
                              hipStream_t stream) {
  const float* x   = (const float*)d_in[0];
  const float* hW1 = (const float*)d_in[1];
  const float* hb1 = (const float*)d_in[2];
  const float* hW2 = (const float*)d_in[3];
  const float* hb2 = (const float*)d_in[4];
  const float* hW3 = (const float*)d_in[5];
  const float* hb3 = (const float*)d_in[6];
  const float* wW1 = (const float*)d_in[7];
  const float* wb1 = (const float*)d_in[8];
  const float* wW2 = (const float*)d_in[9];
  const float* wb2 = (const float*)d_in[10];
  const float* wW3 = (const float*)d_in[11];
  const float* wb3 = (const float*)d_in[12];
  unsigned short* pw = (unsigned short*)d_ws;

  pack_weights<<<816, 64, 0, stream>>>(hW1, wW1, hW2, wW2, hW3, wW3, pw);

  hipFuncSetAttribute((const void*)fused_kernel,
                      hipFuncAttributeMaxDynamicSharedMemorySize, LDS_TOTAL);
  fused_kernel<<<4096, 512, LDS_TOTAL, stream>>>(
      x, hb1, hb2, hb3, wb1, wb2, wb3, pw, (float*)d_out);
}

// Round 3
// 208.668 us; speedup vs baseline: 2.5877x; 1.2366x over previous
//
#include <hip/hip_runtime.h>
#include <cmath>

typedef short short8 __attribute__((ext_vector_type(8)));
typedef short short4v __attribute__((ext_vector_type(4)));
typedef float f32x16 __attribute__((ext_vector_type(16)));

#define EPSF 1.1920929e-07f

// ---------------- LDS layout (bytes), total 141312 (1 block/CU, 16 waves) ----
#define LDS_A2W 0        // [64][264] ushort bf16
#define LDS_A2H 33792    // [64][264] ushort
#define LDS_EW  67584    // [64][8][36] ushort  e = exp(raw_w)   (G3-phase only)
#define LDS_HH  104448   // [64][8][36] ushort  h = softplus+EPS (G3-phase only)
#define LDS_XA  67584    // [64][16] ushort (dead before EW written)
#define LDS_A1  69632    // [64][264] ushort (dead before G3)
#define LDS_TOTAL 141312

// ---------------- packed weights (ushort elements) in d_ws ----------------
// B-frag for mfma_f32_32x32x16_bf16: lane l holds B[k=(l>>5)*8+e][n=l&31]
// tile = 512 ushort, storage [kt][nt][lane][8] per matrix.
#define OFF1H 0        // 8 tiles   (K=16: 1 kt x 8 nt)
#define OFF1W 4096
#define OFF2H 8192     // 128 tiles (16 kt x 8 nt)
#define OFF2W 73728
#define OFF3H 139264   // 272 tiles (16 kt x 17 nt, cols>=528 zero)
#define OFF3W 278528   // 256 tiles (16 kt x 16 nt)  -> end 409600 ush = 819200 B

__device__ __forceinline__ unsigned short f2bf(float f) {   // round-half-up, 2 ops
  union { float f; unsigned u; } v; v.f = f;
  return (unsigned short)((v.u + 0x8000u) >> 16);
}
__device__ __forceinline__ float bf2f(unsigned short h) {
  union { unsigned u; float f; } v; v.u = ((unsigned)h) << 16; return v.f;
}

__global__ void pack_weights(const float* __restrict__ hW1, const float* __restrict__ wW1,
                             const float* __restrict__ hW2, const float* __restrict__ wW2,
                             const float* __restrict__ hW3, const float* __restrict__ wW3,
                             unsigned short* __restrict__ out) {
  int tile = blockIdx.x, l = threadIdx.x;
  const float* src; unsigned short* dst; int NT, N, K, base;
  if (tile < 8)        { src = hW1; dst = out + OFF1H; NT = 8;  N = 256; K = 16;  base = tile; }
  else if (tile < 16)  { src = wW1; dst = out + OFF1W; NT = 8;  N = 256; K = 16;  base = tile - 8; }
  else if (tile < 144) { src = hW2; dst = out + OFF2H; NT = 8;  N = 256; K = 256; base = tile - 16; }
  else if (tile < 272) { src = wW2; dst = out + OFF2W; NT = 8;  N = 256; K = 256; base = tile - 144; }
  else if (tile < 544) { src = hW3; dst = out + OFF3H; NT = 17; N = 528; K = 256; base = tile - 272; }
  else                 { src = wW3; dst = out + OFF3W; NT = 16; N = 512; K = 256; base = tile - 544; }
  int nt = base % NT, kt = base / NT;
  int n = nt * 32 + (l & 31);
  int k0 = kt * 16 + (l >> 5) * 8;
  short8 v;
  #pragma unroll
  for (int e = 0; e < 8; e++) {
    float f = (n < N && (k0 + e) < K) ? src[(k0 + e) * N + n] : 0.f;
    v[e] = (short)f2bf(f);
  }
  *(short8*)(dst + (base * 64 + l) * 8) = v;
}

// one 32x32 C-tile: A rows [0,32) of given lds base, B col-tile ct.
template <int KT, int NTB>
__device__ __forceinline__ f32x16 gemm_tile(const unsigned short* __restrict__ A, int apitch,
                                            const unsigned short* __restrict__ pB, int ct) {
  int l = threadIdx.x & 63;
  f32x16 acc = {0.f,0.f,0.f,0.f,0.f,0.f,0.f,0.f,0.f,0.f,0.f,0.f,0.f,0.f,0.f,0.f};
  const unsigned short* aptr = A + (l & 31) * apitch + (l >> 5) * 8;
  const unsigned short* bptr = pB + (ct * 64 + l) * 8;
  #pragma unroll
  for (int kt = 0; kt < KT; kt++) {
    short8 b = *(const short8*)(bptr + kt * (NTB * 512));
    short8 a = *(const short8*)(aptr + kt * 16);
    acc = __builtin_amdgcn_mfma_f32_32x32x16_bf16(a, b, acc, 0, 0, 0);
  }
  return acc;
}

// C layout (m74/m101): col = lane&31, row = (reg&3) + 8*(reg>>2) + 4*(lane>>5)
__device__ __forceinline__ void epi_relu(char* lds, int oOff, f32x16 acc,
                                         const float* __restrict__ bias, int rt, int ct) {
  int l = threadIdx.x & 63;
  int col = ct * 32 + (l & 31);
  float bv = bias[col];
  unsigned short* o = (unsigned short*)(lds + oOff) + col + (rt * 32 + 4 * (l >> 5)) * 264;
  #pragma unroll
  for (int r = 0; r < 16; r++) {
    int row = (r & 3) + 8 * (r >> 2);
    o[row * 264] = f2bf(fmaxf(acc[r] + bv, 0.f));
  }
}

__global__ __launch_bounds__(1024, 4) void fused_kernel(
    const float* __restrict__ x,
    const float* __restrict__ hb1, const float* __restrict__ hb2, const float* __restrict__ hb3,
    const float* __restrict__ wb1, const float* __restrict__ wb2, const float* __restrict__ wb3,
    const unsigned short* __restrict__ pw,
    float* __restrict__ y) {
  extern __shared__ char lds[];
  const int t = threadIdx.x;
  const int w = t >> 6, l = t & 63;
  const int r0 = blockIdx.x * 64;

  // phase 0: load x, emit y even cols, stage xA bf16 [64][16]
  if (t < 512) {
    int row = t >> 3, c4 = t & 7;
    float4 v = *(const float4*)(x + (r0 + row) * 32 + c4 * 4);
    y[(r0 + row) * 32 + c4 * 4] = v.x;
    y[(r0 + row) * 32 + c4 * 4 + 2] = v.z;
    unsigned short* xa = (unsigned short*)(lds + LDS_XA) + row * 16 + c4 * 2;
    xa[0] = f2bf(v.x); xa[1] = f2bf(v.z);
  }
  __syncthreads();

  const int rt = w >> 3, ct = w & 7;
  const unsigned short* XA = (const unsigned short*)(lds + LDS_XA);
  const unsigned short* A1 = (const unsigned short*)(lds + LDS_A1);
  const unsigned short* A2W = (const unsigned short*)(lds + LDS_A2W);
  const unsigned short* A2H = (const unsigned short*)(lds + LDS_A2H);

  { f32x16 a = gemm_tile<1, 8>(XA + rt * 32 * 16, 16, pw + OFF1W, ct);
    epi_relu(lds, LDS_A1, a, wb1, rt, ct); }
  __syncthreads();
  { f32x16 a = gemm_tile<16, 8>(A1 + rt * 32 * 264, 264, pw + OFF2W, ct);
    epi_relu(lds, LDS_A2W, a, wb2, rt, ct); }
  __syncthreads();
  { f32x16 a = gemm_tile<1, 8>(XA + rt * 32 * 16, 16, pw + OFF1H, ct);
    epi_relu(lds, LDS_A1, a, hb1, rt, ct); }
  __syncthreads();
  { f32x16 a = gemm_tile<16, 8>(A1 + rt * 32 * 264, 264, pw + OFF2H, ct);
    epi_relu(lds, LDS_A2H, a, hb2, rt, ct); }
  __syncthreads();

  // ---- G3 + spline, two column-halves (H: d 0..7 then 8..15), B loaded once ----
  #pragma unroll 1
  for (int H = 0; H < 2; H++) {
    // 34 units: u = (q<<1)|rt ; q<8 -> w-net col-tile H*8+q ; q>=8 -> h-net col-tile (q-8)+8H
    for (int u = w; u < 34; u += 16) {
      int urt = u & 1, q = u >> 1;
      int rbase = urt * 32 + 4 * (l >> 5);
      if (q < 8) {
        int ctg = H * 8 + q;
        f32x16 a = gemm_tile<16, 16>(A2W + urt * 32 * 264, 264, pw + OFF3W, ctg);
        int c = ctg * 32 + (l & 31);
        float bv = wb3[c];
        unsigned short* o = (unsigned short*)(lds + LDS_EW) + rbase * 288 + (ctg & 7) * 36 + (l & 31);
        #pragma unroll
        for (int r = 0; r < 16; r++) {
          int row = (r & 3) + 8 * (r >> 2);
          o[row * 288] = f2bf(__expf(a[r] + bv));
        }
      } else {
        int ctg = (q - 8) + 8 * H;
        f32x16 a = gemm_tile<16, 17>(A2H + urt * 32 * 264, 264, pw + OFF3H, ctg);
        int c = ctg * 32 + (l & 31);
        if (c >= 264 * H && c < 264 * (H + 1)) {   // half-owned cols only (<528 implied)
          float bv = hb3[c];
          unsigned d = ((unsigned)c * 993u) >> 15;  // c/33 for c<544
          int j = c - 33 * (int)d;
          unsigned short* o = (unsigned short*)(lds + LDS_HH) + rbase * 288 + ((int)d & 7) * 36 + j;
          #pragma unroll
          for (int r = 0; r < 16; r++) {
            int row = (r & 3) + 8 * (r >> 2);
            float v = a[r] + bv;
            float sp = fmaxf(v, 0.f) + __logf(1.f + __expf(-fabsf(v))) + EPSF;
            o[row * 288] = f2bf(sp);
          }
        }
      }
    }
    __syncthreads();

    // ---- spline: pair (t, t^1) splits k-range; 512 (row,d) pairs ----
    {
      int p = t >> 1, half = t & 1;
      int row = p >> 3, dl = p & 7, dg = H * 8 + dl;
      const unsigned short* EWp = (const unsigned short*)(lds + LDS_EW) + row * 288 + dl * 36 + half * 16;
      const unsigned short* HHp = (const unsigned short*)(lds + LDS_HH) + row * 288 + dl * 36 + half * 16;
      float e[16], hh[17];
      #pragma unroll
      for (int i = 0; i < 4; i++) {
        short4v ev = *(const short4v*)(EWp + i * 4);
        short4v hv = *(const short4v*)(HHp + i * 4);
        #pragma unroll
        for (int jj = 0; jj < 4; jj++) {
          e[i * 4 + jj] = bf2f((unsigned short)ev[jj]);
          hh[i * 4 + jj] = bf2f((unsigned short)hv[jj]);
        }
      }
      hh[16] = bf2f(HHp[16]);
      float se = 0.f;
      #pragma unroll
      for (int k = 0; k < 16; k++) se += e[k];
      float so = __shfl_xor(se, 1);
      float s = se + so;
      float bl = half ? so : 0.f;
      float xbv = x[(r0 + row) * 32 + 2 * dg + 1];
      float xbs = xbv * s;
      int fnd = (xbs >= bl) ? 1 : 0;
      float cl2 = 0.f, sxl = bl, sew = e[0], shl = hh[0], shr = hh[1], scl2 = 0.f;
      #pragma unroll
      for (int k = 0; k < 16; k++) {
        bool cond = (xbs >= bl);
        if (cond) { sxl = bl; sew = e[k]; shl = hh[k]; shr = hh[k + 1]; scl2 = cl2; }
        cl2 += (hh[k] + hh[k + 1]) * e[k];
        bl += e[k];
      }
      float cl2o = __shfl_xor(cl2, 1);
      float S2 = cl2 + cl2o;
      if (half) scl2 += cl2o;            // globalize half1's area prefix
      float o_sxl = __shfl_xor(sxl, 1), o_sew = __shfl_xor(sew, 1);
      float o_shl = __shfl_xor(shl, 1), o_shr = __shfl_xor(shr, 1);
      float o_scl2 = __shfl_xor(scl2, 1);
      int ofnd = __shfl_xor(fnd, 1);
      bool take_other = half ? (fnd == 0) : (ofnd != 0);
      if (take_other) { sxl = o_sxl; sew = o_sew; shl = o_shl; shr = o_shr; scl2 = o_scl2; }
      float alpha = (xbs - sxl) / (sew + EPSF);
      float yv = (scl2 + (alpha * alpha * (shr - shl) + 2.f * alpha * shl) * sew) / S2;
      if (!half) y[(r0 + row) * 32 + 2 * dg + 1] = yv;
    }
    __syncthreads();
  }
}

extern "C" void kernel_launch(void* const* d_in, const int* in_sizes, int n_in,
                              void* d_out, int out_size, void* d_ws, size_t ws_size,
                              hipStream_t stream) {
  const float* x   = (const float*)d_in[0];
  const float* hW1 = (const float*)d_in[1];
  const float* hb1 = (const float*)d_in[2];
  const float* hW2 = (const float*)d_in[3];
  const float* hb2 = (const float*)d_in[4];
  const float* hW3 = (const float*)d_in[5];
  const float* hb3 = (const float*)d_in[6];
  const float* wW1 = (const float*)d_in[7];
  const float* wb1 = (const float*)d_in[8];
  const float* wW2 = (const float*)d_in[9];
  const float* wb2 = (const float*)d_in[10];
  const float* wW3 = (const float*)d_in[11];
  const float* wb3 = (const float*)d_in[12];
  unsigned short* pw = (unsigned short*)d_ws;

  pack_weights<<<800, 64, 0, stream>>>(hW1, wW1, hW2, wW2, hW3, wW3, pw);

  hipFuncSetAttribute((const void*)fused_kernel,
                      hipFuncAttributeMaxDynamicSharedMemorySize, LDS_TOTAL);
  fused_kernel<<<2048, 1024, LDS_TOTAL, stream>>>(
      x, hb1, hb2, hb3, wb1, wb2, wb3, pw, (float*)d_out);
}

// Round 4
// 201.196 us; speedup vs baseline: 2.6838x; 1.0371x over previous
//
#include <hip/hip_runtime.h>
#include <cmath>

typedef short short8 __attribute__((ext_vector_type(8)));
typedef short short4v __attribute__((ext_vector_type(4)));
typedef float f32x16 __attribute__((ext_vector_type(16)));

#define EPSF 1.1920929e-07f

// ---------------- LDS layout (bytes), total 71680 -> 2 blocks/CU ----------------
#define LDS_A2W 0        // [32][264] ushort bf16
#define LDS_A2H 16896    // [32][264] ushort
#define LDS_A1W 33792    // [32][264] ushort (dead after L2 -> EW overlay)
#define LDS_A1H 50688    // [32][264] ushort (dead after L2 -> HH overlay)
#define LDS_EW  33792    // [32][288] ushort e = exp(raw_w), layout dl*36+k
#define LDS_HH  52224    // [32][288] ushort h = softplus+EPS
#define LDS_XA  70656    // [32][16] ushort
#define LDS_TOTAL 71680

// ---------------- packed weights (ushort elements) in d_ws ----------------
// B-frag for mfma_f32_32x32x16_bf16: lane l holds B[k=(l>>5)*8+e][n=l&31]
// tile = 512 ushort; storage order [nt][kt] (kt contiguous -> imm-offset folding)
#define OFF1H 0        // 8 tiles   (K=16: 1 kt x 8 nt)
#define OFF1W 4096
#define OFF2H 8192     // 128 tiles (8 nt x 16 kt)
#define OFF2W 73728
#define OFF3H 139264   // 272 tiles (17 nt x 16 kt, cols>=528 zero)
#define OFF3W 278528   // 256 tiles (16 nt x 16 kt)

__device__ __forceinline__ unsigned short f2bf(float f) {   // round-half-up
  union { float f; unsigned u; } v; v.f = f;
  return (unsigned short)((v.u + 0x8000u) >> 16);
}
__device__ __forceinline__ float bf2f(unsigned short h) {
  union { unsigned u; float f; } v; v.u = ((unsigned)h) << 16; return v.f;
}

__global__ void pack_weights(const float* __restrict__ hW1, const float* __restrict__ wW1,
                             const float* __restrict__ hW2, const float* __restrict__ wW2,
                             const float* __restrict__ hW3, const float* __restrict__ wW3,
                             unsigned short* __restrict__ out) {
  int tile = blockIdx.x, l = threadIdx.x;
  const float* src; unsigned short* dst; int NT, N, K, base;
  if (tile < 8)        { src = hW1; dst = out + OFF1H; NT = 8;  N = 256; K = 16;  base = tile; }
  else if (tile < 16)  { src = wW1; dst = out + OFF1W; NT = 8;  N = 256; K = 16;  base = tile - 8; }
  else if (tile < 144) { src = hW2; dst = out + OFF2H; NT = 8;  N = 256; K = 256; base = tile - 16; }
  else if (tile < 272) { src = wW2; dst = out + OFF2W; NT = 8;  N = 256; K = 256; base = tile - 144; }
  else if (tile < 544) { src = hW3; dst = out + OFF3H; NT = 17; N = 528; K = 256; base = tile - 272; }
  else                 { src = wW3; dst = out + OFF3W; NT = 16; N = 512; K = 256; base = tile - 544; }
  int nt = base % NT, kt = base / NT, KTT = K / 16;
  int n = nt * 32 + (l & 31);
  int k0 = kt * 16 + (l >> 5) * 8;
  short8 v;
  #pragma unroll
  for (int e = 0; e < 8; e++) {
    float f = (n < N && (k0 + e) < K) ? src[(k0 + e) * N + n] : 0.f;
    v[e] = (short)f2bf(f);
  }
  int idx = nt * KTT + kt;
  *(short8*)(dst + (idx * 64 + l) * 8) = v;
}

// one 32x32 C-tile, acc initialized with bias (folds epilogue add)
template <int KT>
__device__ __forceinline__ f32x16 gemm_tile(const unsigned short* __restrict__ A, int apitch,
                                            const unsigned short* __restrict__ pB, int ct,
                                            float init) {
  int l = threadIdx.x & 63;
  f32x16 acc;
  #pragma unroll
  for (int r = 0; r < 16; r++) acc[r] = init;
  const unsigned short* aptr = A + (l & 31) * apitch + (l >> 5) * 8;
  const unsigned short* bptr = pB + (ct * KT * 64 + l) * 8;
  #pragma unroll
  for (int kt = 0; kt < KT; kt++) {
    short8 b = *(const short8*)(bptr + kt * 512);
    short8 a = *(const short8*)(aptr + kt * 16);
    acc = __builtin_amdgcn_mfma_f32_32x32x16_bf16(a, b, acc, 0, 0, 0);
  }
  return acc;
}

// C layout (m74/m101): col = lane&31, row = (reg&3) + 8*(reg>>2) + 4*(lane>>5)
__device__ __forceinline__ void epi_relu(char* lds, int oOff, f32x16 acc, int ct) {
  int l = threadIdx.x & 63;
  int col = ct * 32 + (l & 31);
  unsigned short* o = (unsigned short*)(lds + oOff) + col + 4 * (l >> 5) * 264;
  #pragma unroll
  for (int r = 0; r < 16; r++) {
    int row = (r & 3) + 8 * (r >> 2);
    o[row * 264] = f2bf(fmaxf(acc[r], 0.f));
  }
}

__global__ __launch_bounds__(512, 4) void fused_kernel(
    const float* __restrict__ x,
    const float* __restrict__ hb1, const float* __restrict__ hb2, const float* __restrict__ hb3,
    const float* __restrict__ wb1, const float* __restrict__ wb2, const float* __restrict__ wb3,
    const unsigned short* __restrict__ pw,
    float* __restrict__ y) {
  extern __shared__ char lds[];
  const int t = threadIdx.x;
  const int w = t >> 6, l = t & 63;
  const int r0 = blockIdx.x * 32;

  // phase 0: load x, emit y even cols, stage xA bf16 [32][16]
  if (t < 256) {
    int row = t >> 3, c4 = t & 7;
    float4 v = *(const float4*)(x + (r0 + row) * 32 + c4 * 4);
    y[(r0 + row) * 32 + c4 * 4] = v.x;
    y[(r0 + row) * 32 + c4 * 4 + 2] = v.z;
    unsigned short* xa = (unsigned short*)(lds + LDS_XA) + row * 16 + c4 * 2;
    xa[0] = f2bf(v.x); xa[1] = f2bf(v.z);
  }
  __syncthreads();

  const unsigned short* XA  = (const unsigned short*)(lds + LDS_XA);
  const unsigned short* A1W = (const unsigned short*)(lds + LDS_A1W);
  const unsigned short* A1H = (const unsigned short*)(lds + LDS_A1H);
  const unsigned short* A2W = (const unsigned short*)(lds + LDS_A2W);
  const unsigned short* A2H = (const unsigned short*)(lds + LDS_A2H);
  const int colw = w * 32 + (l & 31);

  // L1 both nets (wave w -> col-tile w of each): XA A-frag shared
  { f32x16 aw = gemm_tile<1>(XA, 16, pw + OFF1W, w, wb1[colw]);
    epi_relu(lds, LDS_A1W, aw, w);
    f32x16 ah = gemm_tile<1>(XA, 16, pw + OFF1H, w, hb1[colw]);
    epi_relu(lds, LDS_A1H, ah, w); }
  __syncthreads();
  // L2 both nets
  { f32x16 aw = gemm_tile<16>(A1W, 264, pw + OFF2W, w, wb2[colw]);
    epi_relu(lds, LDS_A2W, aw, w);
    f32x16 ah = gemm_tile<16>(A1H, 264, pw + OFF2H, w, hb2[colw]);
    epi_relu(lds, LDS_A2H, ah, w); }
  __syncthreads();

  // ---- G3 + spline, two column-halves (H: d 0..7 then 8..15) ----
  #pragma unroll 1
  for (int H = 0; H < 2; H++) {
    for (int u = w; u < 17; u += 8) {
      int rbase = 4 * (l >> 5);
      if (u < 8) {
        int ctg = H * 8 + u;
        f32x16 a = gemm_tile<16>(A2W, 264, pw + OFF3W, ctg, wb3[ctg * 32 + (l & 31)]);
        unsigned short* o = (unsigned short*)(lds + LDS_EW) + rbase * 288 + (ctg & 7) * 36 + (l & 31);
        #pragma unroll
        for (int r = 0; r < 16; r++) {
          int row = (r & 3) + 8 * (r >> 2);
          o[row * 288] = f2bf(__expf(a[r]));
        }
      } else {
        int ctg = (u - 8) + 8 * H;
        int c = ctg * 32 + (l & 31);
        float bv = (c < 528) ? hb3[c] : 0.f;
        f32x16 a = gemm_tile<16>(A2H, 264, pw + OFF3H, ctg, bv);
        if (c >= 264 * H && c < 264 * (H + 1)) {
          unsigned d = ((unsigned)c * 993u) >> 15;  // c/33 for c<544
          int j = c - 33 * (int)d;
          unsigned short* o = (unsigned short*)(lds + LDS_HH) + rbase * 288 + ((int)d & 7) * 36 + j;
          #pragma unroll
          for (int r = 0; r < 16; r++) {
            int row = (r & 3) + 8 * (r >> 2);
            float v = a[r];
            float sp = fmaxf(v, 0.f) + __logf(1.f + __expf(-fabsf(v))) + EPSF;
            o[row * 288] = f2bf(sp);
          }
        }
      }
    }
    __syncthreads();

    // ---- spline: pair (t, t^1) splits k-range; 256 (row,d) pairs ----
    {
      int p = t >> 1, half = t & 1;
      int row = p >> 3, dl = p & 7, dg = H * 8 + dl;
      const unsigned short* EWb = (const unsigned short*)(lds + LDS_EW) + row * 288 + dl * 36;
      const unsigned short* HHb = (const unsigned short*)(lds + LDS_HH) + row * 288 + dl * 36;
      const unsigned short* EWp = EWb + half * 16;
      const unsigned short* HHp = HHb + half * 16;
      float e[16], hh[17];
      #pragma unroll
      for (int i = 0; i < 4; i++) {
        short4v ev = *(const short4v*)(EWp + i * 4);
        short4v hv = *(const short4v*)(HHp + i * 4);
        #pragma unroll
        for (int jj = 0; jj < 4; jj++) {
          e[i * 4 + jj] = bf2f((unsigned short)ev[jj]);
          hh[i * 4 + jj] = bf2f((unsigned short)hv[jj]);
        }
      }
      hh[16] = bf2f(HHp[16]);
      float se = 0.f;
      #pragma unroll
      for (int k = 0; k < 16; k++) se += e[k];
      float so = __shfl_xor(se, 1);
      float s = se + so;
      float xbv = x[(r0 + row) * 32 + 2 * dg + 1];
      float xbs = xbv * s;
      float bl0 = half ? so : 0.f;
      int fnd = (xbs >= bl0) ? 1 : 0;   // monotone bins: found <=> first cmp true
      float bl = bl0, cl2 = 0.f, sxl = bl0, scl2 = 0.f;
      int ki = 0;
      #pragma unroll
      for (int k = 0; k < 16; k++) {
        bool c = (xbs >= bl);
        ki   = c ? k   : ki;
        sxl  = c ? bl  : sxl;
        scl2 = c ? cl2 : scl2;
        cl2 += (hh[k] + hh[k + 1]) * e[k];
        bl  += e[k];
      }
      float cl2o = __shfl_xor(cl2, 1);
      float S2 = cl2 + cl2o;
      if (half) scl2 += cl2o;            // globalize half1's area prefix
      int   o_ki   = __shfl_xor(ki, 1);
      float o_sxl  = __shfl_xor(sxl, 1);
      float o_scl2 = __shfl_xor(scl2, 1);
      int   o_fnd  = __shfl_xor(fnd, 1);
      bool other = half ? (fnd == 0) : (o_fnd != 0);
      int   gki   = other ? o_ki   : ki;
      int   ghalf = other ? (half ^ 1) : half;
      float gsxl  = other ? o_sxl  : sxl;
      float gscl2 = other ? o_scl2 : scl2;
      int go = ghalf * 16 + gki;
      float sew = bf2f(EWb[go]);
      float shl = bf2f(HHb[go]);
      float shr = bf2f(HHb[go + 1]);
      float alpha = (xbs - gsxl) / (sew + EPSF);
      float yv = (gscl2 + (alpha * alpha * (shr - shl) + 2.f * alpha * shl) * sew) / S2;
      if (!half) y[(r0 + row) * 32 + 2 * dg + 1] = yv;
    }
    __syncthreads();
  }
}

extern "C" void kernel_launch(void* const* d_in, const int* in_sizes, int n_in,
                              void* d_out, int out_size, void* d_ws, size_t ws_size,
                              hipStream_t stream) {
  const float* x   = (const float*)d_in[0];
  const float* hW1 = (const float*)d_in[1];
  const float* hb1 = (const float*)d_in[2];
  const float* hW2 = (const float*)d_in[3];
  const float* hb2 = (const float*)d_in[4];
  const float* hW3 = (const float*)d_in[5];
  const float* hb3 = (const float*)d_in[6];
  const float* wW1 = (const float*)d_in[7];
  const float* wb1 = (const float*)d_in[8];
  const float* wW2 = (const float*)d_in[9];
  const float* wb2 = (const float*)d_in[10];
  const float* wW3 = (const float*)d_in[11];
  const float* wb3 = (const float*)d_in[12];
  unsigned short* pw = (unsigned short*)d_ws;

  pack_weights<<<800, 64, 0, stream>>>(hW1, wW1, hW2, wW2, hW3, wW3, pw);

  hipFuncSetAttribute((const void*)fused_kernel,
                      hipFuncAttributeMaxDynamicSharedMemorySize, LDS_TOTAL);
  fused_kernel<<<4096, 512, LDS_TOTAL, stream>>>(
      x, hb1, hb2, hb3, wb1, wb2, wb3, pw, (float*)d_out);
}

// Round 5
// 190.510 us; speedup vs baseline: 2.8343x; 1.0561x over previous
//
#include <hip/hip_runtime.h>
#include <cmath>

typedef short short8 __attribute__((ext_vector_type(8)));
typedef short short4v __attribute__((ext_vector_type(4)));
typedef float f32x16 __attribute__((ext_vector_type(16)));

#define EPSF 1.1920929e-07f

// ---------------- LDS layout (bytes), total 141312 (M=64, 1 block/CU) --------
#define LDS_A2W 0        // [64][264] ushort bf16
#define LDS_A2H 33792    // [64][264] ushort
#define LDS_A1W 67584    // [64][264] ushort (dead after L2)
#define LDS_A1H 101376   // [64][264] ushort (dead after L2)
#define LDS_XA  135168   // [64][16]  ushort (dead after L1)
#define LDS_EW  67584    // [64][288] ushort e = exp(raw_w)   (overlays A1W)
#define LDS_HH  104448   // [64][288] ushort h = softplus+EPS (overlays A1H+XA)
#define LDS_TOTAL 141312

// ---------------- packed weights (ushort elements) in d_ws ----------------
// B-frag for mfma_f32_32x32x16_bf16: lane l holds B[k=(l>>5)*8+e][n=l&31]
// tile = 512 ushort; storage order [nt][kt] (kt contiguous -> imm-offset folding)
#define OFF1H 0        // 8 tiles   (K=16: 1 kt x 8 nt)
#define OFF1W 4096
#define OFF2H 8192     // 128 tiles (8 nt x 16 kt)
#define OFF2W 73728
#define OFF3H 139264   // 272 tiles (17 nt x 16 kt, cols>=528 zero)
#define OFF3W 278528   // 256 tiles (16 nt x 16 kt)

__device__ __forceinline__ unsigned short f2bf(float f) {   // round-half-up
  union { float f; unsigned u; } v; v.f = f;
  return (unsigned short)((v.u + 0x8000u) >> 16);
}
__device__ __forceinline__ float bf2f(unsigned short h) {
  union { unsigned u; float f; } v; v.u = ((unsigned)h) << 16; return v.f;
}

__global__ void pack_weights(const float* __restrict__ hW1, const float* __restrict__ wW1,
                             const float* __restrict__ hW2, const float* __restrict__ wW2,
                             const float* __restrict__ hW3, const float* __restrict__ wW3,
                             unsigned short* __restrict__ out) {
  int tile = blockIdx.x, l = threadIdx.x;
  const float* src; unsigned short* dst; int NT, N, K, base;
  if (tile < 8)        { src = hW1; dst = out + OFF1H; NT = 8;  N = 256; K = 16;  base = tile; }
  else if (tile < 16)  { src = wW1; dst = out + OFF1W; NT = 8;  N = 256; K = 16;  base = tile - 8; }
  else if (tile < 144) { src = hW2; dst = out + OFF2H; NT = 8;  N = 256; K = 256; base = tile - 16; }
  else if (tile < 272) { src = wW2; dst = out + OFF2W; NT = 8;  N = 256; K = 256; base = tile - 144; }
  else if (tile < 544) { src = hW3; dst = out + OFF3H; NT = 17; N = 528; K = 256; base = tile - 272; }
  else                 { src = wW3; dst = out + OFF3W; NT = 16; N = 512; K = 256; base = tile - 544; }
  int nt = base % NT, kt = base / NT, KTT = K / 16;
  int n = nt * 32 + (l & 31);
  int k0 = kt * 16 + (l >> 5) * 8;
  short8 v;
  #pragma unroll
  for (int e = 0; e < 8; e++) {
    float f = (n < N && (k0 + e) < K) ? src[(k0 + e) * N + n] : 0.f;
    v[e] = (short)f2bf(f);
  }
  int idx = nt * KTT + kt;
  *(short8*)(dst + (idx * 64 + l) * 8) = v;
}

struct Acc2 { f32x16 a0, a1; };

// two 32x32 C-tiles (rows 0-31 and 32-63) sharing every B fragment
template <int KT>
__device__ __forceinline__ Acc2 gemm_tile2(const unsigned short* __restrict__ A, int apitch,
                                           const unsigned short* __restrict__ pB, int ct,
                                           float init) {
  int l = threadIdx.x & 63;
  Acc2 r;
  #pragma unroll
  for (int i = 0; i < 16; i++) { r.a0[i] = init; r.a1[i] = init; }
  const unsigned short* aptr0 = A + (l & 31) * apitch + (l >> 5) * 8;
  const unsigned short* aptr1 = aptr0 + 32 * apitch;
  const unsigned short* bptr = pB + (ct * KT * 64 + l) * 8;
  #pragma unroll
  for (int kt = 0; kt < KT; kt++) {
    short8 b = *(const short8*)(bptr + kt * 512);
    short8 a0 = *(const short8*)(aptr0 + kt * 16);
    short8 a1 = *(const short8*)(aptr1 + kt * 16);
    r.a0 = __builtin_amdgcn_mfma_f32_32x32x16_bf16(a0, b, r.a0, 0, 0, 0);
    r.a1 = __builtin_amdgcn_mfma_f32_32x32x16_bf16(a1, b, r.a1, 0, 0, 0);
  }
  return r;
}

// C layout (m74/m101): col = lane&31, row = (reg&3) + 8*(reg>>2) + 4*(lane>>5)
__device__ __forceinline__ void epi_relu2(char* lds, int oOff, Acc2 a, int ct) {
  int l = threadIdx.x & 63;
  int col = ct * 32 + (l & 31);
  unsigned short* o = (unsigned short*)(lds + oOff) + col + 4 * (l >> 5) * 264;
  #pragma unroll
  for (int r = 0; r < 16; r++) {
    int row = (r & 3) + 8 * (r >> 2);
    o[row * 264] = f2bf(fmaxf(a.a0[r], 0.f));
    o[(row + 32) * 264] = f2bf(fmaxf(a.a1[r], 0.f));
  }
}

__global__ __launch_bounds__(1024, 4) void fused_kernel(
    const float* __restrict__ x,
    const float* __restrict__ hb1, const float* __restrict__ hb2, const float* __restrict__ hb3,
    const float* __restrict__ wb1, const float* __restrict__ wb2, const float* __restrict__ wb3,
    const unsigned short* __restrict__ pw,
    float* __restrict__ y) {
  extern __shared__ char lds[];
  const int t = threadIdx.x;
  const int w = t >> 6, l = t & 63;
  const int r0 = blockIdx.x * 64;

  // phase 0: load x, emit y even cols, stage xA bf16 [64][16]
  if (t < 512) {
    int row = t >> 3, c4 = t & 7;
    float4 v = *(const float4*)(x + (r0 + row) * 32 + c4 * 4);
    y[(r0 + row) * 32 + c4 * 4] = v.x;
    y[(r0 + row) * 32 + c4 * 4 + 2] = v.z;
    unsigned short* xa = (unsigned short*)(lds + LDS_XA) + row * 16 + c4 * 2;
    xa[0] = f2bf(v.x); xa[1] = f2bf(v.z);
  }
  __syncthreads();

  const unsigned short* XA  = (const unsigned short*)(lds + LDS_XA);
  const unsigned short* A1W = (const unsigned short*)(lds + LDS_A1W);
  const unsigned short* A1H = (const unsigned short*)(lds + LDS_A1H);
  const unsigned short* A2W = (const unsigned short*)(lds + LDS_A2W);
  const unsigned short* A2H = (const unsigned short*)(lds + LDS_A2H);
  const int ct8 = w & 7;
  const int col8 = ct8 * 32 + (l & 31);

  // L1: waves 0-7 w-net, waves 8-15 h-net (each one col-tile, both row-tiles)
  if (w < 8) { epi_relu2(lds, LDS_A1W, gemm_tile2<1>(XA, 16, pw + OFF1W, ct8, wb1[col8]), ct8); }
  else       { epi_relu2(lds, LDS_A1H, gemm_tile2<1>(XA, 16, pw + OFF1H, ct8, hb1[col8]), ct8); }
  __syncthreads();
  // L2
  if (w < 8) { epi_relu2(lds, LDS_A2W, gemm_tile2<16>(A1W, 264, pw + OFF2W, ct8, wb2[col8]), ct8); }
  else       { epi_relu2(lds, LDS_A2H, gemm_tile2<16>(A1H, 264, pw + OFF2H, ct8, hb2[col8]), ct8); }
  __syncthreads();

  // ---- G3 + spline, two column-halves (H: d 0..7 then 8..15) ----
  #pragma unroll 1
  for (int H = 0; H < 2; H++) {
    for (int u = w; u < 17; u += 16) {
      if (u < 8) {
        int ctg = H * 8 + u;
        Acc2 a = gemm_tile2<16>(A2W, 264, pw + OFF3W, ctg, wb3[ctg * 32 + (l & 31)]);
        unsigned short* o = (unsigned short*)(lds + LDS_EW) + (ctg & 7) * 36 + (l & 31)
                            + 4 * (l >> 5) * 288;
        #pragma unroll
        for (int r = 0; r < 16; r++) {
          int row = (r & 3) + 8 * (r >> 2);
          o[row * 288] = f2bf(__expf(a.a0[r]));
          o[(row + 32) * 288] = f2bf(__expf(a.a1[r]));
        }
      } else {
        int ctg = (u - 8) + 8 * H;
        int c = ctg * 32 + (l & 31);
        float bv = (c < 528) ? hb3[c] : 0.f;
        Acc2 a = gemm_tile2<16>(A2H, 264, pw + OFF3H, ctg, bv);
        if (c >= 264 * H && c < 264 * (H + 1)) {
          unsigned d = ((unsigned)c * 993u) >> 15;  // c/33 for c<544
          int j = c - 33 * (int)d;
          unsigned short* o = (unsigned short*)(lds + LDS_HH) + ((int)d & 7) * 36 + j
                              + 4 * (l >> 5) * 288;
          #pragma unroll
          for (int r = 0; r < 16; r++) {
            int row = (r & 3) + 8 * (r >> 2);
            float v0 = a.a0[r];
            o[row * 288] = f2bf(fmaxf(v0, 0.f) + __logf(1.f + __expf(-fabsf(v0))) + EPSF);
            float v1 = a.a1[r];
            o[(row + 32) * 288] = f2bf(fmaxf(v1, 0.f) + __logf(1.f + __expf(-fabsf(v1))) + EPSF);
          }
        }
      }
    }
    __syncthreads();

    // ---- spline: pair (t, t^1) splits k-range; 512 (row,d) pairs ----
    {
      int p = t >> 1, half = t & 1;
      int row = p >> 3, dl = p & 7, dg = H * 8 + dl;
      const unsigned short* EWb = (const unsigned short*)(lds + LDS_EW) + row * 288 + dl * 36;
      const unsigned short* HHb = (const unsigned short*)(lds + LDS_HH) + row * 288 + dl * 36;
      const unsigned short* EWp = EWb + half * 16;
      const unsigned short* HHp = HHb + half * 16;
      float e[16], hh[17];
      #pragma unroll
      for (int i = 0; i < 4; i++) {
        short4v ev = *(const short4v*)(EWp + i * 4);
        short4v hv = *(const short4v*)(HHp + i * 4);
        #pragma unroll
        for (int jj = 0; jj < 4; jj++) {
          e[i * 4 + jj] = bf2f((unsigned short)ev[jj]);
          hh[i * 4 + jj] = bf2f((unsigned short)hv[jj]);
        }
      }
      hh[16] = bf2f(HHp[16]);
      float se = 0.f;
      #pragma unroll
      for (int k = 0; k < 16; k++) se += e[k];
      float so = __shfl_xor(se, 1);
      float s = se + so;
      float xbv = x[(r0 + row) * 32 + 2 * dg + 1];
      float xbs = xbv * s;
      float bl0 = half ? so : 0.f;
      int fnd = (xbs >= bl0) ? 1 : 0;
      float bl = bl0, cl2 = 0.f, sxl = bl0, scl2 = 0.f;
      int ki = 0;
      #pragma unroll
      for (int k = 0; k < 16; k++) {
        bool c = (xbs >= bl);
        ki   = c ? k   : ki;
        sxl  = c ? bl  : sxl;
        scl2 = c ? cl2 : scl2;
        cl2 += (hh[k] + hh[k + 1]) * e[k];
        bl  += e[k];
      }
      float cl2o = __shfl_xor(cl2, 1);
      float S2 = cl2 + cl2o;
      if (half) scl2 += cl2o;
      int   o_ki   = __shfl_xor(ki, 1);
      float o_sxl  = __shfl_xor(sxl, 1);
      float o_scl2 = __shfl_xor(scl2, 1);
      int   o_fnd  = __shfl_xor(fnd, 1);
      bool other = half ? (fnd == 0) : (o_fnd != 0);
      int   gki   = other ? o_ki   : ki;
      int   ghalf = other ? (half ^ 1) : half;
      float gsxl  = other ? o_sxl  : sxl;
      float gscl2 = other ? o_scl2 : scl2;
      int go = ghalf * 16 + gki;
      float sew = bf2f(EWb[go]);
      float shl = bf2f(HHb[go]);
      float shr = bf2f(HHb[go + 1]);
      float alpha = (xbs - gsxl) / (sew + EPSF);
      float yv = (gscl2 + (alpha * alpha * (shr - shl) + 2.f * alpha * shl) * sew) / S2;
      if (!half) y[(r0 + row) * 32 + 2 * dg + 1] = yv;
    }
    __syncthreads();
  }
}

extern "C" void kernel_launch(void* const* d_in, const int* in_sizes, int n_in,
                              void* d_out, int out_size, void* d_ws, size_t ws_size,
                              hipStream_t stream) {
  const float* x   = (const float*)d_in[0];
  const float* hW1 = (const float*)d_in[1];
  const float* hb1 = (const float*)d_in[2];
  const float* hW2 = (const float*)d_in[3];
  const float* hb2 = (const float*)d_in[4];
  const float* hW3 = (const float*)d_in[5];
  const float* hb3 = (const float*)d_in[6];
  const float* wW1 = (const float*)d_in[7];
  const float* wb1 = (const float*)d_in[8];
  const float* wW2 = (const float*)d_in[9];
  const float* wb2 = (const float*)d_in[10];
  const float* wW3 = (const float*)d_in[11];
  const float* wb3 = (const float*)d_in[12];
  unsigned short* pw = (unsigned short*)d_ws;

  pack_weights<<<800, 64, 0, stream>>>(hW1, wW1, hW2, wW2, hW3, wW3, pw);

  hipFuncSetAttribute((const void*)fused_kernel,
                      hipFuncAttributeMaxDynamicSharedMemorySize, LDS_TOTAL);
  fused_kernel<<<2048, 1024, LDS_TOTAL, stream>>>(
      x, hb1, hb2, hb3, wb1, wb2, wb3, pw, (float*)d_out);
}